// Round 1
// baseline (209.224 us; speedup 1.0000x reference)
//
#include <hip/hip_runtime.h>
#include <math.h>

namespace {
constexpr int NB = 256;   // batch
constexpr int NR = 1152;  // routes (input capsules)
constexpr int NC = 10;    // output capsules
constexpr int NO = 16;    // output dim
constexpr int NI = 8;     // input dim
constexpr int WROW = NO * NI;      // 128 floats per (r,c)
constexpr int NCHUNK = 32;         // r-chunks for partial kernel
constexpr int RCH = NR / NCHUNK;   // 36 r per chunk
}

// b = 0, c = 1/R  (softmax of zeros over R)
__global__ __launch_bounds__(256) void k_init(float* __restrict__ bbuf,
                                              float* __restrict__ cbuf) {
    int i = blockIdx.x * 256 + threadIdx.x;
    if (i < NR * NC) { bbuf[i] = 0.0f; cbuf[i] = 1.0f / NR; }
}

// xT[r][b][i] = x[b][r][i]
__global__ __launch_bounds__(256) void k_transpose(const float* __restrict__ x,
                                                   float* __restrict__ xT) {
    int r = blockIdx.x;
    int b = threadIdx.x;
    const float4* src = reinterpret_cast<const float4*>(x + ((size_t)b * NR + r) * NI);
    float4*       dst = reinterpret_cast<float4*>(xT + ((size_t)r * NB + b) * NI);
    dst[0] = src[0];
    dst[1] = src[1];
}

// part[c][ch][b][o] = sum_{r in chunk} c[r,c] * sum_i W[r,c,o,i] * x[b,r,i]
__global__ __launch_bounds__(256) void k_partial(const float* __restrict__ xT,
                                                 const float* __restrict__ W,
                                                 const float* __restrict__ cbuf,
                                                 float* __restrict__ part) {
    const int c  = blockIdx.x;   // 0..9
    const int ch = blockIdx.y;   // 0..31
    const int r0 = ch * RCH;
    const int b  = threadIdx.x;

    __shared__ float Ws[RCH * WROW];   // 36*128 floats = 18.4 KB, c-scaled

    for (int idx = threadIdx.x; idx < RCH * WROW; idx += 256) {
        int rr = idx >> 7;
        int j  = idx & 127;
        int r  = r0 + rr;
        Ws[idx] = cbuf[r * NC + c] * W[((size_t)r * NC + c) * WROW + j];
    }
    __syncthreads();

    float acc[NO];
    #pragma unroll
    for (int o = 0; o < NO; ++o) acc[o] = 0.0f;

    for (int rr = 0; rr < RCH; ++rr) {
        const float4* xp = reinterpret_cast<const float4*>(
            xT + ((size_t)(r0 + rr) * NB + b) * NI);
        float4 xa = xp[0];
        float4 xb = xp[1];
        const float* wrow = &Ws[rr * WROW];
        #pragma unroll
        for (int o = 0; o < NO; ++o) {
            const float4* wp = reinterpret_cast<const float4*>(wrow + o * NI);
            float4 w0 = wp[0];
            float4 w1 = wp[1];
            acc[o] += w0.x * xa.x + w0.y * xa.y + w0.z * xa.z + w0.w * xa.w
                    + w1.x * xb.x + w1.y * xb.y + w1.z * xb.z + w1.w * xb.w;
        }
    }

    float4* pout = reinterpret_cast<float4*>(
        part + (((size_t)c * NCHUNK + ch) * NB + b) * NO);
    #pragma unroll
    for (int q = 0; q < 4; ++q) {
        pout[q] = make_float4(acc[q * 4 + 0], acc[q * 4 + 1],
                              acc[q * 4 + 2], acc[q * 4 + 3]);
    }
}

// s[c,b,o] = sum_ch part ; v = squash(s); write vbuf[c][b][o] or out[b][c][o]
__global__ __launch_bounds__(256) void k_reduce(const float* __restrict__ part,
                                                float* __restrict__ vbuf,
                                                float* __restrict__ out,
                                                int final_pass) {
    int gid = blockIdx.x * 256 + threadIdx.x;   // 0..40959, gid=(c*NB+b)*NO+o
    int o  = gid & 15;
    int cb = gid >> 4;
    int b  = cb & 255;
    int c  = cb >> 8;
    float s = 0.0f;
    const float* p = part + (size_t)c * NCHUNK * NB * NO + (size_t)b * NO + o;
    #pragma unroll
    for (int ch = 0; ch < NCHUNK; ++ch) s += p[(size_t)ch * NB * NO];
    float v = s * fabsf(s) / (1.0f + s * s);
    if (final_pass) {
        out[((size_t)b * NC + c) * NO + o] = v;
    } else {
        vbuf[gid] = v;
    }
}

// bbuf[r,c] += (1/B) * sum_b sum_o (sum_i W[r,c,o,i] x[b,r,i]) * v[c,b,o]
__global__ __launch_bounds__(256) void k_agree(const float* __restrict__ xT,
                                               const float* __restrict__ W,
                                               const float* __restrict__ vbuf,
                                               float* __restrict__ bbuf) {
    const int c  = blockIdx.x;        // 10
    const int r0 = blockIdx.y * 8;    // 144 groups of 8 r
    const int b  = threadIdx.x;

    __shared__ float Ws[8 * WROW];    // 1024 floats
    {
        int t  = threadIdx.x;
        int rr = t >> 5;
        int j4 = t & 31;
        const float4* src = reinterpret_cast<const float4*>(
            W + ((size_t)(r0 + rr) * NC + c) * WROW) + j4;
        reinterpret_cast<float4*>(Ws)[t] = src[0];
    }
    __syncthreads();

    float vv[NO];
    {
        const float4* vp = reinterpret_cast<const float4*>(
            vbuf + ((size_t)c * NB + b) * NO);
        #pragma unroll
        for (int q = 0; q < 4; ++q) {
            float4 t4 = vp[q];
            vv[q * 4 + 0] = t4.x; vv[q * 4 + 1] = t4.y;
            vv[q * 4 + 2] = t4.z; vv[q * 4 + 3] = t4.w;
        }
    }

    float partl[8];
    #pragma unroll
    for (int rr = 0; rr < 8; ++rr) {
        const float4* xp = reinterpret_cast<const float4*>(
            xT + ((size_t)(r0 + rr) * NB + b) * NI);
        float4 xa = xp[0], xb2 = xp[1];
        const float* wrow = &Ws[rr * WROW];
        float p = 0.0f;
        #pragma unroll
        for (int o = 0; o < NO; ++o) {
            const float4* wp = reinterpret_cast<const float4*>(wrow + o * NI);
            float4 w0 = wp[0], w1 = wp[1];
            float dot = w0.x * xa.x + w0.y * xa.y + w0.z * xa.z + w0.w * xa.w
                      + w1.x * xb2.x + w1.y * xb2.y + w1.z * xb2.z + w1.w * xb2.w;
            p += vv[o] * dot;
        }
        partl[rr] = p;
    }

    #pragma unroll
    for (int rr = 0; rr < 8; ++rr) {
        float p = partl[rr];
        p += __shfl_xor(p, 1);
        p += __shfl_xor(p, 2);
        p += __shfl_xor(p, 4);
        p += __shfl_xor(p, 8);
        p += __shfl_xor(p, 16);
        p += __shfl_xor(p, 32);
        partl[rr] = p;
    }
    __shared__ float red[4][8];
    int wave = threadIdx.x >> 6;
    int lane = threadIdx.x & 63;
    if (lane == 0) {
        #pragma unroll
        for (int rr = 0; rr < 8; ++rr) red[wave][rr] = partl[rr];
    }
    __syncthreads();
    if (threadIdx.x < 8) {
        int rr = threadIdx.x;
        float a = red[0][rr] + red[1][rr] + red[2][rr] + red[3][rr];
        bbuf[(r0 + rr) * NC + c] += a * (1.0f / NB);
    }
}

// softmax over r (axis 0) per column c
__global__ __launch_bounds__(256) void k_softmax(const float* __restrict__ bbuf,
                                                 float* __restrict__ cbuf) {
    const int c   = blockIdx.x;
    const int tid = threadIdx.x;
    __shared__ float sred[4];
    __shared__ float sred2[4];
    int wave = tid >> 6, lane = tid & 63;

    float m = -1e30f;
    for (int r = tid; r < NR; r += 256) m = fmaxf(m, bbuf[r * NC + c]);
    #pragma unroll
    for (int off = 1; off < 64; off <<= 1) m = fmaxf(m, __shfl_xor(m, off));
    if (lane == 0) sred[wave] = m;
    __syncthreads();
    m = fmaxf(fmaxf(sred[0], sred[1]), fmaxf(sred[2], sred[3]));

    float s = 0.0f;
    for (int r = tid; r < NR; r += 256) {
        float e = expf(bbuf[r * NC + c] - m);
        cbuf[r * NC + c] = e;
        s += e;
    }
    #pragma unroll
    for (int off = 1; off < 64; off <<= 1) s += __shfl_xor(s, off);
    if (lane == 0) sred2[wave] = s;
    __syncthreads();
    s = sred2[0] + sred2[1] + sred2[2] + sred2[3];
    float inv = 1.0f / s;
    for (int r = tid; r < NR; r += 256) cbuf[r * NC + c] *= inv;
}

extern "C" void kernel_launch(void* const* d_in, const int* in_sizes, int n_in,
                              void* d_out, int out_size, void* d_ws, size_t ws_size,
                              hipStream_t stream) {
    const float* x = (const float*)d_in[0];   // [256,1152,8]
    const float* W = (const float*)d_in[1];   // [1152,10,16,8]
    float* out = (float*)d_out;               // [256,10,16,1]

    float* xT   = (float*)d_ws;                              // NR*NB*NI
    float* part = xT + (size_t)NR * NB * NI;                 // NC*NCHUNK*NB*NO
    float* bbuf = part + (size_t)NC * NCHUNK * NB * NO;      // NR*NC
    float* cbuf = bbuf + (size_t)NR * NC;                    // NR*NC
    float* vbuf = cbuf + (size_t)NR * NC;                    // NC*NB*NO

    k_init<<<(NR * NC + 255) / 256, 256, 0, stream>>>(bbuf, cbuf);
    k_transpose<<<NR, 256, 0, stream>>>(x, xT);

    dim3 gpart(NC, NCHUNK);
    dim3 gagree(NC, NR / 8);
    int  gred = (NC * NB * NO) / 256;   // 160 blocks

    for (int it = 0; it < 3; ++it) {
        k_partial<<<gpart, 256, 0, stream>>>(xT, W, cbuf, part);
        k_reduce<<<gred, 256, 0, stream>>>(part, vbuf, out, it == 2 ? 1 : 0);
        if (it < 2) {
            k_agree<<<gagree, 256, 0, stream>>>(xT, W, vbuf, bbuf);
            k_softmax<<<NC, 256, 0, stream>>>(bbuf, cbuf);
        }
    }
}